// Round 1
// baseline (737.025 us; speedup 1.0000x reference)
//
#include <hip/hip_runtime.h>
#include <hip/hip_bf16.h>

#define DEVB 64
#define LSEQ 512
#define DDIM 600

typedef short short8 __attribute__((ext_vector_type(8)));
typedef float f32x4 __attribute__((ext_vector_type(4)));

constexpr int LDP = 40;   // padded LDS row stride (bf16 elems): 80 B = 20 dwords -> 2-way max conflict

__device__ __forceinline__ unsigned short f2bf(float x) {
    union { float f; unsigned u; } v; v.f = x;
    unsigned r = v.u + 0x7fffu + ((v.u >> 16) & 1u);   // RNE
    return (unsigned short)(r >> 16);
}
__device__ __forceinline__ float bf2f(unsigned short h) {
    union { unsigned u; float f; } v; v.u = ((unsigned)h) << 16; return v.f;
}
__device__ __forceinline__ void cvt_hilo(float x, unsigned short& hi, unsigned short& lo) {
    hi = f2bf(x);
    lo = f2bf(x - bf2f(hi));
}
__device__ __forceinline__ f32x4 mfma16(short8 a, short8 b, f32x4 c) {
    return __builtin_amdgcn_mfma_f32_16x16x32_bf16(a, b, c, 0, 0, 0);
}

// ---------------------------------------------------------------------------
// K1: attn[b][p][h] = sum_d P[b][p][d] * H[b][h][d]   (fp32 out, hi/lo bf16 MFMA)
// ---------------------------------------------------------------------------
__global__ __launch_bounds__(256) void attn_gemm(
    const float* __restrict__ P, const float* __restrict__ H,
    float* __restrict__ attn)
{
    const int blk = blockIdx.x;
    const int b  = blk >> 4;
    const int pt = ((blk >> 2) & 3) << 7;
    const int ht = (blk & 3) << 7;
    const float* Pb = P + (size_t)b * LSEQ * DDIM;
    const float* Hb = H + (size_t)b * LSEQ * DDIM;
    float* Ab = attn + (size_t)b * LSEQ * LSEQ;

    __shared__ unsigned short Ahi[128 * LDP], Alo[128 * LDP];
    __shared__ unsigned short Bhi[128 * LDP], Blo[128 * LDP];

    const int t    = threadIdx.x;
    const int lane = t & 63;
    const int wave = t >> 6;
    const int wm = (wave >> 1) << 6;
    const int wn = (wave & 1) << 6;
    const int fr = lane & 15;
    const int fq = lane >> 4;

    f32x4 acc[4][4];
#pragma unroll
    for (int i = 0; i < 4; ++i)
#pragma unroll
        for (int j = 0; j < 4; ++j) acc[i][j] = (f32x4){0.f, 0.f, 0.f, 0.f};

    for (int k0 = 0; k0 < DDIM; k0 += 32) {
        const bool full = (k0 + 32 <= DDIM);
#pragma unroll
        for (int r = 0; r < 4; ++r) {
            int idx = t + (r << 8);
            int row = idx >> 3;
            int c4  = (idx & 7) << 2;
            // A tile (P)
            {
                const float* src = Pb + (size_t)(pt + row) * DDIM + k0 + c4;
                float x0, x1, x2, x3;
                if (full) { float4 v = *(const float4*)src; x0 = v.x; x1 = v.y; x2 = v.z; x3 = v.w; }
                else {
                    x0 = (k0 + c4 + 0 < DDIM) ? src[0] : 0.f;
                    x1 = (k0 + c4 + 1 < DDIM) ? src[1] : 0.f;
                    x2 = (k0 + c4 + 2 < DDIM) ? src[2] : 0.f;
                    x3 = (k0 + c4 + 3 < DDIM) ? src[3] : 0.f;
                }
                ushort4 hi, lo;
                cvt_hilo(x0, hi.x, lo.x);
                cvt_hilo(x1, hi.y, lo.y);
                cvt_hilo(x2, hi.z, lo.z);
                cvt_hilo(x3, hi.w, lo.w);
                *(ushort4*)&Ahi[row * LDP + c4] = hi;
                *(ushort4*)&Alo[row * LDP + c4] = lo;
            }
            // B tile (H)
            {
                const float* src = Hb + (size_t)(ht + row) * DDIM + k0 + c4;
                float x0, x1, x2, x3;
                if (full) { float4 v = *(const float4*)src; x0 = v.x; x1 = v.y; x2 = v.z; x3 = v.w; }
                else {
                    x0 = (k0 + c4 + 0 < DDIM) ? src[0] : 0.f;
                    x1 = (k0 + c4 + 1 < DDIM) ? src[1] : 0.f;
                    x2 = (k0 + c4 + 2 < DDIM) ? src[2] : 0.f;
                    x3 = (k0 + c4 + 3 < DDIM) ? src[3] : 0.f;
                }
                ushort4 hi, lo;
                cvt_hilo(x0, hi.x, lo.x);
                cvt_hilo(x1, hi.y, lo.y);
                cvt_hilo(x2, hi.z, lo.z);
                cvt_hilo(x3, hi.w, lo.w);
                *(ushort4*)&Bhi[row * LDP + c4] = hi;
                *(ushort4*)&Blo[row * LDP + c4] = lo;
            }
        }
        __syncthreads();

        short8 ah[4], al[4], bh[4], bl[4];
#pragma unroll
        for (int i = 0; i < 4; ++i) {
            ah[i] = *(const short8*)&Ahi[(wm + (i << 4) + fr) * LDP + (fq << 3)];
            al[i] = *(const short8*)&Alo[(wm + (i << 4) + fr) * LDP + (fq << 3)];
            bh[i] = *(const short8*)&Bhi[(wn + (i << 4) + fr) * LDP + (fq << 3)];
            bl[i] = *(const short8*)&Blo[(wn + (i << 4) + fr) * LDP + (fq << 3)];
        }
#pragma unroll
        for (int mi = 0; mi < 4; ++mi)
#pragma unroll
            for (int ni = 0; ni < 4; ++ni) {
                f32x4 c = acc[mi][ni];
                c = mfma16(ah[mi], bh[ni], c);
                c = mfma16(ah[mi], bl[ni], c);
                c = mfma16(al[mi], bh[ni], c);
                acc[mi][ni] = c;
            }
        __syncthreads();
    }

#pragma unroll
    for (int mi = 0; mi < 4; ++mi)
#pragma unroll
        for (int ni = 0; ni < 4; ++ni)
#pragma unroll
            for (int j = 0; j < 4; ++j) {
                int p = pt + wm + (mi << 4) + (fq << 2) + j;
                int h = ht + wn + (ni << 4) + fr;
                Ab[(size_t)p * LSEQ + h] = acc[mi][ni][j];
            }
}

// ---------------------------------------------------------------------------
// K2: per (b,p) row stats over h:  M = max(s*m), R = 1/(T + EPS*S)
// ---------------------------------------------------------------------------
__global__ __launch_bounds__(256) void row_stats(
    const float* __restrict__ attn, const float* __restrict__ hmask,
    float* __restrict__ M1, float* __restrict__ R1)
{
    int rowid = (blockIdx.x << 2) + (threadIdx.x >> 6);
    int lane  = threadIdx.x & 63;
    int b     = rowid >> 9;
    const float* row = attn + (size_t)rowid * LSEQ;
    const float* hm  = hmask + (b << 9);

    float4 s0 = *(const float4*)(row + (lane << 3));
    float4 s1 = *(const float4*)(row + (lane << 3) + 4);
    float4 m0 = *(const float4*)(hm + (lane << 3));
    float4 m1 = *(const float4*)(hm + (lane << 3) + 4);

    float v[8], mk[8];
    v[0] = s0.x * m0.x; mk[0] = m0.x;
    v[1] = s0.y * m0.y; mk[1] = m0.y;
    v[2] = s0.z * m0.z; mk[2] = m0.z;
    v[3] = s0.w * m0.w; mk[3] = m0.w;
    v[4] = s1.x * m1.x; mk[4] = m1.x;
    v[5] = s1.y * m1.y; mk[5] = m1.y;
    v[6] = s1.z * m1.z; mk[6] = m1.z;
    v[7] = s1.w * m1.w; mk[7] = m1.w;

    float mx = -1e30f;
#pragma unroll
    for (int i = 0; i < 8; ++i) mx = fmaxf(mx, v[i]);
#pragma unroll
    for (int off = 32; off; off >>= 1) mx = fmaxf(mx, __shfl_xor(mx, off));

    float T = 0.f, S = 0.f;
#pragma unroll
    for (int i = 0; i < 8; ++i) {
        float e = __expf(v[i] - mx);
        S += e;
        T += mk[i] * e;
    }
#pragma unroll
    for (int off = 32; off; off >>= 1) { T += __shfl_xor(T, off); S += __shfl_xor(S, off); }

    if (lane == 0) {
        M1[rowid] = mx;
        R1[rowid] = 1.f / (T + 1e-13f * S);
    }
}

// ---------------------------------------------------------------------------
// K3: per (b,h) column stats over p (online masked softmax stats)
// ---------------------------------------------------------------------------
__global__ __launch_bounds__(256) void col_stats(
    const float* __restrict__ attn, const float* __restrict__ pmask,
    float* __restrict__ M2, float* __restrict__ R2)
{
    int b  = blockIdx.x >> 3;
    int h0 = (blockIdx.x & 7) << 6;
    int lane = threadIdx.x & 63;
    int wave = threadIdx.x >> 6;
    int h = h0 + lane;
    const float* Ab = attn + (size_t)b * LSEQ * LSEQ;
    const float* pm = pmask + (b << 9);

    float mx[4] = {-1e30f, -1e30f, -1e30f, -1e30f};
    float T[4]  = {0.f, 0.f, 0.f, 0.f};
    float S[4]  = {0.f, 0.f, 0.f, 0.f};

    for (int p = wave << 7; p < (wave << 7) + 128; p += 4) {
#pragma unroll
        for (int j = 0; j < 4; ++j) {
            float s = Ab[(size_t)(p + j) * LSEQ + h];
            float m = pm[p + j];
            float v = s * m;
            float nm = fmaxf(mx[j], v);
            float sc = __expf(mx[j] - nm);
            float e  = __expf(v - nm);
            T[j] = T[j] * sc + m * e;
            S[j] = S[j] * sc + e;
            mx[j] = nm;
        }
    }
    float gm = fmaxf(fmaxf(mx[0], mx[1]), fmaxf(mx[2], mx[3]));
    float gT = 0.f, gS = 0.f;
#pragma unroll
    for (int j = 0; j < 4; ++j) {
        float sc = __expf(mx[j] - gm);
        gT += T[j] * sc;
        gS += S[j] * sc;
    }

    __shared__ float sM[4][64], sT[4][64], sS[4][64];
    sM[wave][lane] = gm; sT[wave][lane] = gT; sS[wave][lane] = gS;
    __syncthreads();
    if (wave == 0) {
        float fm = sM[0][lane];
#pragma unroll
        for (int w = 1; w < 4; ++w) fm = fmaxf(fm, sM[w][lane]);
        float fT = 0.f, fS = 0.f;
#pragma unroll
        for (int w = 0; w < 4; ++w) {
            float sc = __expf(sM[w][lane] - fm);
            fT += sT[w][lane] * sc;
            fS += sS[w][lane] * sc;
        }
        M2[(b << 9) + h] = fm;
        R2[(b << 9) + h] = 1.f / (fT + 1e-13f * fS);
    }
}

// ---------------------------------------------------------------------------
// K4/K5: out[b][m][d] = mask_m[m] * sum_k w(m,k) * Bsrc[b][k][d]
//   w(m,k) = mask_k[k] ? exp(attnval - M[m]) * R[m] : 0
//   TRANSA=0: attnval = attn[b][m][k]   (weighted premise,  k = h, Bsrc = H)
//   TRANSA=1: attnval = attn[b][k][m]   (weighted hypothesis, k = p, Bsrc = P)
// ---------------------------------------------------------------------------
template <int TRANSA>
__global__ __launch_bounds__(256) void wsum(
    const float* __restrict__ attn, const float* __restrict__ Bsrc,
    const float* __restrict__ mask_k, const float* __restrict__ mask_m,
    const float* __restrict__ Mst, const float* __restrict__ Rst,
    float* __restrict__ out)
{
    const int blk = blockIdx.x;
    const int b   = blk / 20;
    const int rem = blk % 20;
    const int m0  = (rem / 5) << 7;
    const int n0  = (rem % 5) << 7;

    const float* Ab  = attn + (size_t)b * LSEQ * LSEQ;
    const float* Bb  = Bsrc + (size_t)b * LSEQ * DDIM;
    const float* mkb = mask_k + (b << 9);

    __shared__ unsigned short Wl[128 * LDP];
    __shared__ unsigned short Bl[128 * LDP];
    __shared__ float Ml[128], Rl[128], Mm[128];

    const int t    = threadIdx.x;
    const int lane = t & 63;
    const int wave = t >> 6;
    const int wm = (wave >> 1) << 6;
    const int wn = (wave & 1) << 6;
    const int fr = lane & 15;
    const int fq = lane >> 4;

    if (t < 128) {
        Ml[t] = Mst[(b << 9) + m0 + t];
        Rl[t] = Rst[(b << 9) + m0 + t];
        Mm[t] = mask_m[(b << 9) + m0 + t];
    }
    __syncthreads();

    f32x4 acc[4][4];
#pragma unroll
    for (int i = 0; i < 4; ++i)
#pragma unroll
        for (int j = 0; j < 4; ++j) acc[i][j] = (f32x4){0.f, 0.f, 0.f, 0.f};

    for (int k0 = 0; k0 < LSEQ; k0 += 32) {
        // ---- A tile: softmax weights -> bf16, LDS layout [m][k]
        if constexpr (TRANSA == 0) {
#pragma unroll
            for (int r = 0; r < 4; ++r) {
                int idx = t + (r << 8);
                int row = idx >> 3;
                int c4  = (idx & 7) << 2;
                float4 x  = *(const float4*)(Ab + (size_t)(m0 + row) * LSEQ + k0 + c4);
                float4 km = *(const float4*)(mkb + k0 + c4);
                float Mv = Ml[row], Rv = Rl[row];
                ushort4 w;
                w.x = (km.x != 0.f) ? f2bf(__expf(x.x - Mv) * Rv) : (unsigned short)0;
                w.y = (km.y != 0.f) ? f2bf(__expf(x.y - Mv) * Rv) : (unsigned short)0;
                w.z = (km.z != 0.f) ? f2bf(__expf(x.z - Mv) * Rv) : (unsigned short)0;
                w.w = (km.w != 0.f) ? f2bf(__expf(x.w - Mv) * Rv) : (unsigned short)0;
                *(ushort4*)&Wl[row * LDP + c4] = w;
            }
        } else {
#pragma unroll
            for (int r = 0; r < 4; ++r) {
                int mh = t & 127;
                int pq = (t >> 7) + (r << 1);
                float Mv = Ml[mh], Rv = Rl[mh];
                ushort4 w;
#pragma unroll
                for (int j = 0; j < 4; ++j) {
                    int k = k0 + (pq << 2) + j;
                    float x  = Ab[(size_t)k * LSEQ + m0 + mh];
                    float km = mkb[k];
                    ((unsigned short*)&w)[j] =
                        (km != 0.f) ? f2bf(__expf(x - Mv) * Rv) : (unsigned short)0;
                }
                *(ushort4*)&Wl[mh * LDP + (pq << 2)] = w;
            }
        }
        // ---- B tile: Bsrc[k][n] -> LDS layout [n][k] (transposed), bf16
#pragma unroll
        for (int r = 0; r < 4; ++r) {
            int d  = t & 127;
            int kq = (t >> 7) + (r << 1);
            bool valid = (n0 + d) < DDIM;
            ushort4 v;
#pragma unroll
            for (int j = 0; j < 4; ++j) {
                int k = k0 + (kq << 2) + j;
                float x = valid ? Bb[(size_t)k * DDIM + n0 + d] : 0.f;
                ((unsigned short*)&v)[j] = f2bf(x);
            }
            *(ushort4*)&Bl[d * LDP + (kq << 2)] = v;
        }
        __syncthreads();

        short8 af[4], bfr[4];
#pragma unroll
        for (int i = 0; i < 4; ++i) {
            af[i]  = *(const short8*)&Wl[(wm + (i << 4) + fr) * LDP + (fq << 3)];
            bfr[i] = *(const short8*)&Bl[(wn + (i << 4) + fr) * LDP + (fq << 3)];
        }
#pragma unroll
        for (int mi = 0; mi < 4; ++mi)
#pragma unroll
            for (int ni = 0; ni < 4; ++ni)
                acc[mi][ni] = mfma16(af[mi], bfr[ni], acc[mi][ni]);
        __syncthreads();
    }

#pragma unroll
    for (int mi = 0; mi < 4; ++mi)
#pragma unroll
        for (int j = 0; j < 4; ++j) {
            int row = wm + (mi << 4) + (fq << 2) + j;
            float mm = Mm[row];
#pragma unroll
            for (int ni = 0; ni < 4; ++ni) {
                int d = n0 + wn + (ni << 4) + fr;
                if (d < DDIM)
                    out[((size_t)(b << 9) + m0 + row) * DDIM + d] = mm * acc[mi][ni][j];
            }
        }
}

// ---------------------------------------------------------------------------
extern "C" void kernel_launch(void* const* d_in, const int* in_sizes, int n_in,
                              void* d_out, int out_size, void* d_ws, size_t ws_size,
                              hipStream_t stream)
{
    const float* P  = (const float*)d_in[0];   // encoded_premise   [64,512,600]
    const float* pm = (const float*)d_in[1];   // premise_mask      [64,512]
    const float* H  = (const float*)d_in[2];   // encoded_hypothesis[64,512,600]
    const float* hm = (const float*)d_in[3];   // hypothesis_mask   [64,512]
    float* out = (float*)d_out;

    float* attn = (float*)d_ws;                       // 64*512*512 fp32 = 64 MiB
    float* M1 = attn + (size_t)DEVB * LSEQ * LSEQ;
    float* R1 = M1 + DEVB * LSEQ;
    float* M2 = R1 + DEVB * LSEQ;
    float* R2 = M2 + DEVB * LSEQ;

    attn_gemm<<<DEVB * 16, 256, 0, stream>>>(P, H, attn);
    row_stats<<<DEVB * LSEQ / 4, 256, 0, stream>>>(attn, hm, M1, R1);
    col_stats<<<DEVB * 8, 256, 0, stream>>>(attn, pm, M2, R2);
    wsum<0><<<DEVB * 20, 256, 0, stream>>>(attn, H, hm, pm, M1, R1, out);
    wsum<1><<<DEVB * 20, 256, 0, stream>>>(attn, P, pm, hm, M2, R2,
                                           out + (size_t)DEVB * LSEQ * DDIM);
}